// Round 3
// baseline (9554.926 us; speedup 1.0000x reference)
//
#include <hip/hip_runtime.h>
#include <hip/hip_bf16.h>

// ---------------- problem constants ----------------
#define UNITS   400
#define BATCH   128
#define TSTEPS  1000
#define GATES   1600            // 4*UNITS
#define KCAP    448             // padded K capacity: 13 MFMA K-tiles of 32 + pad (zeros)
#define NGROUP  8               // batch groups (128/16)
#define WPG     100             // waves per group (each owns 4 units = 16 repacked cols)
#define ROWS    16              // batch rows per group
#define OUTSZ   (BATCH*TSTEPS*3)
#define NSLICE  5               // out-partial slices (contention splitting)
#define SPIN_GUARD 8192         // poll-iteration cap: ~4M cy/step worst case; normal is 1-10 iters

typedef __bf16 bf16x8 __attribute__((ext_vector_type(8)));
typedef float  f32x4  __attribute__((ext_vector_type(4)));
typedef unsigned long long ull;

__device__ __forceinline__ float sigm(float v)     { return 1.f / (1.f + __expf(-v)); }
__device__ __forceinline__ float tanhfast(float v) { return 1.f - 2.f / (1.f + __expf(2.f * v)); }

__device__ __forceinline__ unsigned short f2bf(float v) {
    __hip_bfloat16 h = __float2bfloat16(v);
    return *reinterpret_cast<unsigned short*>(&h);
}

// ---------------- init / repack kernel ----------------
// Urep: [1600][448] bf16 k-major (col = unit*4 + gate), zero-padded k>=400
// Wrep: [3][1600] f32 repacked; brep: [1600] f32 repacked
// Hbuf: 2 x [128][448] bf16 zeroed; flags: 8*128 ints zeroed; outP: 5*[384000] f32 zeroed
__global__ void hw_init_kernel(const float* __restrict__ U, const float* __restrict__ W,
                               const float* __restrict__ b,
                               unsigned short* __restrict__ Urep, float* __restrict__ Wrep,
                               float* __restrict__ brep, unsigned short* __restrict__ Hbuf,
                               int* __restrict__ flags, float* __restrict__ outP)
{
    int idx = blockIdx.x * 256 + threadIdx.x;
    if (idx < GATES * KCAP) {
        int col = idx / KCAP, k = idx - col * KCAP;
        int u = col >> 2, G = col & 3;
        float v = (k < UNITS) ? U[k * GATES + G * UNITS + u] : 0.f;
        Urep[idx] = f2bf(v);
        return;
    }
    idx -= GATES * KCAP;
    if (idx < 3 * GATES) {
        int f = idx / GATES, col = idx - f * GATES;
        int u = col >> 2, G = col & 3;
        Wrep[idx] = W[f * GATES + G * UNITS + u];
        return;
    }
    idx -= 3 * GATES;
    if (idx < GATES) {
        int u = idx >> 2, G = idx & 3;
        brep[idx] = b[G * UNITS + u];
        return;
    }
    idx -= GATES;
    if (idx < 2 * BATCH * KCAP) { Hbuf[idx] = 0; return; }
    idx -= 2 * BATCH * KCAP;
    if (idx < NGROUP * 128) { flags[idx] = 0; return; }
    idx -= NGROUP * 128;
    if (idx < NSLICE * OUTSZ) { outP[idx] = 0.f; return; }
}

// coherent 16B load (bypass L1+L2 -> LLC)
#define LDA(i, offlit) \
    asm volatile("global_load_dwordx4 %0, %1, off offset:" offlit " sc0 sc1" \
                 : "=v"(af[i]) : "v"(ab) : "memory");

// ---------------- persistent LSTM kernel: 800 independent waves ----------------
// bid&7 = group (16 batch rows), bid>>3 = wave index widx (4 units = 16 cols)
__global__ __launch_bounds__(64) void lstm_kernel(
    const float* __restrict__ x,                    // [128][1000][3]
    const float* __restrict__ p_i, const float* __restrict__ p_f, const float* __restrict__ p_o,
    const float* __restrict__ Wd,                   // [400][3]
    const unsigned short* __restrict__ Urep,        // [1600][448] bf16
    const float* __restrict__ Wrep, const float* __restrict__ brep,
    unsigned short* __restrict__ Hbuf,              // 2 x [128][448] bf16
    int* __restrict__ flags,                        // [8][128]
    float* __restrict__ outP)                       // [5][128][1000][3]
{
    const int lane = threadIdx.x;
    const int bid  = blockIdx.x;
    const int grp  = bid & 7;
    const int widx = bid >> 3;          // 0..99
    const int b0   = grp * ROWS;
    const int ub   = widx * 4;          // first unit of this wave
    const int col0 = widx * 16;         // repacked col base (= ub*4)
    const int row  = lane & 15;
    const int kg   = lane >> 4;         // 0..3 (k-group for frags; unit-local for pointwise)
    const int gu   = ub + kg;           // this thread's unit (pointwise role)

    // ---- resident U B-fragments: 13 K-tiles x 16 cols ----
    bf16x8 barr[13];
    {
        const unsigned short* up = Urep + (size_t)(col0 + row) * KCAP + kg * 8;
        #pragma unroll
        for (int kt = 0; kt < 13; ++kt)
            barr[kt] = *(const bf16x8*)(up + kt * 32);
    }

    // ---- per-thread constants ----
    float w0[4], w1[4], w2[4], bz[4];
    #pragma unroll
    for (int G = 0; G < 4; ++G) {
        w0[G] = Wrep[0 * GATES + gu * 4 + G];
        w1[G] = Wrep[1 * GATES + gu * 4 + G];
        w2[G] = Wrep[2 * GATES + gu * 4 + G];
        bz[G] = brep[gu * 4 + G];
    }
    const float pi = p_i[gu], pf = p_f[gu], po = p_o[gu];
    const float wd0 = Wd[gu * 3 + 0], wd1 = Wd[gu * 3 + 1], wd2 = Wd[gu * 3 + 2];

    // ---- addresses ----
    const size_t bufbytes = (size_t)BATCH * KCAP * 2;
    const char* arb0 = (const char*)Hbuf + ((size_t)(b0 + row) * KCAP + kg * 8) * 2;
    const char* arb1 = arb0 + bufbytes;
    char* awb0 = (char*)Hbuf + ((size_t)(b0 + lane) * KCAP + ub) * 2;   // lane<16 only
    char* awb1 = awb0 + bufbytes;

    int* fl    = flags + grp * 128;
    int* slotp = fl + widx;
    const float* xp  = x + (size_t)(b0 + row) * (TSTEPS * 3);
    float* opp = outP + (size_t)(widx % NSLICE) * OUTSZ + (size_t)(b0 + row) * (TSTEPS * 3);

    const int S = ((lane & 12) << 2) + (kg << 2);   // z-exchange source lane base
    const int jj = lane & 3;
    float cst = 0.f;

    #pragma unroll 1
    for (int t = 0; t < TSTEPS; ++t) {
        // x for this step (off critical path, issues before poll)
        float x0 = xp[t * 3 + 0], x1 = xp[t * 3 + 1], x2 = xp[t * 3 + 2];

        // ---- poll group slots: all >= t  =>  h(t-1) fully in buf[t&1] ----
        // Guarded spin: never trips in correct operation; converts a protocol
        // stall into a visible wrong-result failure instead of a queue hang.
        {
            int f0, f1, guard = 0;
            bool ok;
            do {
                f0 = __hip_atomic_load(fl + lane, __ATOMIC_RELAXED, __HIP_MEMORY_SCOPE_AGENT);
                f1 = (lane < WPG - 64)
                     ? __hip_atomic_load(fl + 64 + lane, __ATOMIC_RELAXED, __HIP_MEMORY_SCOPE_AGENT)
                     : t;
                ok = __all(f0 >= t && f1 >= t);
            } while (!ok && ++guard < SPIN_GUARD);
        }

        // ---- A-fragments direct global->reg (coherent) ----
        f32x4 af[13];
        const char* ab = (t & 1) ? arb1 : arb0;
        LDA(0, "0")   LDA(1, "64")  LDA(2, "128") LDA(3, "192")
        LDA(4, "256") LDA(5, "320") LDA(6, "384") LDA(7, "448")
        LDA(8, "512") LDA(9, "576") LDA(10, "640") LDA(11, "704") LDA(12, "768")
        asm volatile("s_waitcnt vmcnt(0)" ::: "memory");
        __builtin_amdgcn_sched_barrier(0);

        // ---- z = h @ U_slice (two accumulator chains) ----
        f32x4 a0 = {0.f, 0.f, 0.f, 0.f}, a1 = {0.f, 0.f, 0.f, 0.f};
        #pragma unroll
        for (int kt = 0; kt < 13; kt += 2)
            a0 = __builtin_amdgcn_mfma_f32_16x16x32_bf16(
                     __builtin_bit_cast(bf16x8, af[kt]), barr[kt], a0, 0, 0, 0);
        #pragma unroll
        for (int kt = 1; kt < 13; kt += 2)
            a1 = __builtin_amdgcn_mfma_f32_16x16x32_bf16(
                     __builtin_bit_cast(bf16x8, af[kt]), barr[kt], a1, 0, 0, 0);
        f32x4 acc = a0 + a1;

        // ---- in-wave z exchange: (row,u) thread gathers its 4 gate values ----
        // C layout: lane lm holds C[(lm>>4)*4+j][lm&15]; (row,c) lives in
        // lane (row>>2)*16 + c, reg j=row&3. This thread wants c = kg*4+G.
        float zz[4];
        {
            float q0[4], q1[4], q2[4], q3[4];
            #pragma unroll
            for (int G = 0; G < 4; ++G) {
                q0[G] = __shfl(acc[0], S + G);
                q1[G] = __shfl(acc[1], S + G);
                q2[G] = __shfl(acc[2], S + G);
                q3[G] = __shfl(acc[3], S + G);
            }
            #pragma unroll
            for (int G = 0; G < 4; ++G) {
                float r = q0[G];
                r = (jj == 1) ? q1[G] : r;
                r = (jj == 2) ? q2[G] : r;
                r = (jj == 3) ? q3[G] : r;
                zz[G] = r + bz[G] + x0 * w0[G] + x1 * w1[G] + x2 * w2[G];
            }
        }

        // ---- pointwise peephole LSTM cell ----
        float iv = sigm(zz[0] + pi * cst);
        float fv = sigm(zz[1] + pf * cst);
        float cn = fv * cst + iv * tanhfast(zz[2]);
        float ov = sigm(zz[3] + po * cn);
        float h  = ov * tanhfast(cn);
        cst = cn;

        // ---- h broadcast: pack this wave's 4 units per row into one 8B store ----
        int hb = (int)f2bf(h);
        int h1 = __shfl_down(hb, 16);
        int h2 = __shfl_down(hb, 32);
        int h3 = __shfl_down(hb, 48);
        if (lane < 16) {
            unsigned int lo = (unsigned int)(hb & 0xffff) | ((unsigned int)(h1 & 0xffff) << 16);
            unsigned int hi = (unsigned int)(h2 & 0xffff) | ((unsigned int)(h3 & 0xffff) << 16);
            ull pk = (ull)lo | ((ull)hi << 32);
            ull* dst = (ull*)((t & 1) ? awb0 : awb1);   // write buf[(t+1)&1]
            __hip_atomic_store(dst, pk, __ATOMIC_RELAXED, __HIP_MEMORY_SCOPE_AGENT);
        }
        asm volatile("s_waitcnt vmcnt(0)" ::: "memory");   // h at LLC before flag
        if (lane == 0)
            __hip_atomic_store(slotp, t + 1, __ATOMIC_RELAXED, __HIP_MEMORY_SCOPE_AGENT);

        // ---- fused projection partials (after flag: off critical path) ----
        float s0 = h * wd0, s1 = h * wd1, s2 = h * wd2;
        s0 += __shfl_xor(s0, 16); s0 += __shfl_xor(s0, 32);
        s1 += __shfl_xor(s1, 16); s1 += __shfl_xor(s1, 32);
        s2 += __shfl_xor(s2, 16); s2 += __shfl_xor(s2, 32);
        if (lane < 16) {
            atomicAdd(opp + t * 3 + 0, s0);
            atomicAdd(opp + t * 3 + 1, s1);
            atomicAdd(opp + t * 3 + 2, s2);
        }
    }
}

// ---------------- merge: out = bd + sum of 5 slices ----------------
__global__ void merge_kernel(const float* __restrict__ outP, const float* __restrict__ bd,
                             float* __restrict__ out)
{
    int i = blockIdx.x * 256 + threadIdx.x;
    if (i >= OUTSZ) return;
    float s = bd[i % 3];
    #pragma unroll
    for (int k = 0; k < NSLICE; ++k) s += outP[(size_t)k * OUTSZ + i];
    out[i] = s;
}

// ---------------- launch ----------------
extern "C" void kernel_launch(void* const* d_in, const int* in_sizes, int n_in,
                              void* d_out, int out_size, void* d_ws, size_t ws_size,
                              hipStream_t stream)
{
    const float* x   = (const float*)d_in[0];
    const float* W   = (const float*)d_in[1];
    const float* U   = (const float*)d_in[2];
    const float* b   = (const float*)d_in[3];
    const float* p_i = (const float*)d_in[4];
    const float* p_f = (const float*)d_in[5];
    const float* p_o = (const float*)d_in[6];
    const float* Wd  = (const float*)d_in[7];
    const float* bd  = (const float*)d_in[8];
    float* out = (float*)d_out;

    char* p = (char*)d_ws;
    unsigned short* Urep = (unsigned short*)p;  p += (size_t)GATES * KCAP * 2;      // 1,433,600
    float* Wrep = (float*)p;                    p += (size_t)3 * GATES * 4;         // 19,200
    float* brep = (float*)p;                    p += (size_t)GATES * 4;             // 6,400
    unsigned short* Hbuf = (unsigned short*)p;  p += (size_t)2 * BATCH * KCAP * 2;  // 229,376
    int* flags = (int*)p;                       p += (size_t)NGROUP * 128 * 4;      // 4,096
    float* outP = (float*)p;                    p += (size_t)NSLICE * OUTSZ * 4;    // 7,680,000

    const int total = GATES * KCAP + 3 * GATES + GATES + 2 * BATCH * KCAP
                    + NGROUP * 128 + NSLICE * OUTSZ;
    const int iblocks = (total + 255) / 256;
    hipLaunchKernelGGL(hw_init_kernel, dim3(iblocks), dim3(256), 0, stream,
                       U, W, b, Urep, Wrep, brep, Hbuf, flags, outP);

    hipLaunchKernelGGL(lstm_kernel, dim3(NGROUP * WPG), dim3(64), 0, stream,
                       x, p_i, p_f, p_o, Wd, Urep, Wrep, brep, Hbuf, flags, outP);

    hipLaunchKernelGGL(merge_kernel, dim3((OUTSZ + 255) / 256), dim3(256), 0, stream,
                       outP, bd, out);
}

// Round 4
// 3718.472 us; speedup vs baseline: 2.5696x; 2.5696x over previous
//
#include <hip/hip_runtime.h>
#include <hip/hip_bf16.h>

// ---------------- problem constants ----------------
#define UNITS   400
#define BATCH   128
#define TSTEPS  1000
#define GATES   1600            // 4*UNITS
#define KCAP    448             // padded K capacity: 13 MFMA K-tiles of 32 + pad (zeros)
#define NGROUP  8               // batch groups (128/16)
#define CWG     20              // WGs per group (each owns 20 units)
#define SU      20              // units per WG
#define UW      4               // units per wave
#define NW      5               // waves per WG
#define NTHR    320
#define ROWS    16              // batch rows per group
#define OUTSZ   (BATCH*TSTEPS*3)
#define NSLICE  5               // out-partial slices (contention splitting)
#define SPIN_GUARD 16384        // poll cap; never trips in correct operation

typedef __bf16 bf16x8 __attribute__((ext_vector_type(8)));
typedef float  f32x4  __attribute__((ext_vector_type(4)));
typedef unsigned long long ull;

__device__ __forceinline__ float sigm(float v)     { return 1.f / (1.f + __expf(-v)); }
__device__ __forceinline__ float tanhfast(float v) { return 1.f - 2.f / (1.f + __expf(2.f * v)); }

__device__ __forceinline__ unsigned short f2bf(float v) {
    __hip_bfloat16 h = __float2bfloat16(v);
    return *reinterpret_cast<unsigned short*>(&h);
}

// ---------------- init / repack kernel ----------------
// Urep: [1600][448] bf16 k-major (col = unit*4 + gate), zero-padded k>=400
// Wrep: [3][1600] f32 repacked; brep: [1600] f32 repacked
// Hbuf: 2 x [128][448] bf16 zeroed; flags: 8*128 ints zeroed; outP: 5*[384000] f32 zeroed
__global__ void hw_init_kernel(const float* __restrict__ U, const float* __restrict__ W,
                               const float* __restrict__ b,
                               unsigned short* __restrict__ Urep, float* __restrict__ Wrep,
                               float* __restrict__ brep, unsigned short* __restrict__ Hbuf,
                               int* __restrict__ flags, float* __restrict__ outP)
{
    int idx = blockIdx.x * 256 + threadIdx.x;
    if (idx < GATES * KCAP) {
        int col = idx / KCAP, k = idx - col * KCAP;
        int u = col >> 2, G = col & 3;
        float v = (k < UNITS) ? U[k * GATES + G * UNITS + u] : 0.f;
        Urep[idx] = f2bf(v);
        return;
    }
    idx -= GATES * KCAP;
    if (idx < 3 * GATES) {
        int f = idx / GATES, col = idx - f * GATES;
        int u = col >> 2, G = col & 3;
        Wrep[idx] = W[f * GATES + G * UNITS + u];
        return;
    }
    idx -= 3 * GATES;
    if (idx < GATES) {
        int u = idx >> 2, G = idx & 3;
        brep[idx] = b[G * UNITS + u];
        return;
    }
    idx -= GATES;
    if (idx < 2 * BATCH * KCAP) { Hbuf[idx] = 0; return; }
    idx -= 2 * BATCH * KCAP;
    if (idx < NGROUP * 128) { flags[idx] = 0; return; }
    idx -= NGROUP * 128;
    if (idx < NSLICE * OUTSZ) { outP[idx] = 0.f; return; }
}

// coherent 16B load (bypass L1+L2 -> LLC)
#define LDA(i, offlit) \
    asm volatile("global_load_dwordx4 %0, %1, off offset:" offlit " sc0 sc1" \
                 : "=v"(af[i]) : "v"(ab) : "memory");

// ---------------- persistent LSTM kernel ----------------
// 160 WGs x 320 threads. bid&7 = group (16 batch rows), bid>>3 = c (20 units).
// Wave wid owns units c*20 + wid*4 .. +3 (16 repacked cols).
__global__ __launch_bounds__(NTHR, 1) void lstm_kernel(
    const float* __restrict__ x,                    // [128][1000][3]
    const float* __restrict__ p_i, const float* __restrict__ p_f, const float* __restrict__ p_o,
    const float* __restrict__ Wd,                   // [400][3]
    const unsigned short* __restrict__ Urep,        // [1600][448] bf16
    const float* __restrict__ Wrep, const float* __restrict__ brep,
    unsigned short* __restrict__ Hbuf,              // 2 x [128][448] bf16
    int* __restrict__ flags,                        // [8][128]
    float* __restrict__ outP)                       // [5][128][1000][3]
{
    __shared__ float redw[NW * ROWS * 3];           // 960 B

    const int tid  = threadIdx.x;
    const int lane = tid & 63, wid = tid >> 6;
    const int bid  = blockIdx.x;
    const int grp  = bid & 7;
    const int c    = bid >> 3;          // 0..19
    const int b0   = grp * ROWS;
    const int uw   = c * SU + wid * UW; // wave's first unit
    const int col0 = uw * 4;            // wave's repacked col base
    const int row  = lane & 15;
    const int kg   = lane >> 4;         // 0..3
    const int gu   = uw + kg;           // this thread's unit (pointwise role)

    // ---- resident U B-fragments: 13 K-tiles x 16 cols ----
    bf16x8 barr[13];
    {
        const unsigned short* up = Urep + (size_t)(col0 + row) * KCAP + kg * 8;
        #pragma unroll
        for (int kt = 0; kt < 13; ++kt)
            barr[kt] = *(const bf16x8*)(up + kt * 32);
    }

    // ---- per-thread constants ----
    float w0[4], w1[4], w2[4], bz[4];
    #pragma unroll
    for (int G = 0; G < 4; ++G) {
        w0[G] = Wrep[0 * GATES + gu * 4 + G];
        w1[G] = Wrep[1 * GATES + gu * 4 + G];
        w2[G] = Wrep[2 * GATES + gu * 4 + G];
        bz[G] = brep[gu * 4 + G];
    }
    const float pi = p_i[gu], pf = p_f[gu], po = p_o[gu];
    const float wd0 = Wd[gu * 3 + 0], wd1 = Wd[gu * 3 + 1], wd2 = Wd[gu * 3 + 2];

    // ---- addresses ----
    const size_t bufbytes = (size_t)BATCH * KCAP * 2;
    const char* arb0 = (const char*)Hbuf + ((size_t)(b0 + row) * KCAP + kg * 8) * 2;
    const char* arb1 = arb0 + bufbytes;
    char* awb0 = (char*)Hbuf + ((size_t)(b0 + lane) * KCAP + uw) * 2;   // lane<16 only
    char* awb1 = awb0 + bufbytes;

    int* fl    = flags + grp * 128;
    int* slotp = fl + c;
    const int pidx = (lane < CWG) ? lane : 0;
    const float* xp = x + (size_t)(b0 + row) * (TSTEPS * 3);
    float* opp = outP + (size_t)(c % NSLICE) * OUTSZ + (size_t)b0 * (TSTEPS * 3);

    const int S  = ((lane & 12) << 2) + (kg << 2);  // z-exchange source lane base
    const int jj = lane & 3;
    float cst = 0.f;

    #pragma unroll 1
    for (int t = 0; t < TSTEPS; ++t) {
        // x for this step (issues before poll; off critical path)
        float x0 = xp[t * 3 + 0], x1 = xp[t * 3 + 1], x2 = xp[t * 3 + 2];

        // ---- poll 20 group slots (2 cache lines): all >= t  =>  buf[t&1] ready ----
        {
            int guard = 0;
            for (;;) {
                int f = __hip_atomic_load(fl + pidx, __ATOMIC_RELAXED, __HIP_MEMORY_SCOPE_AGENT);
                if (__all(f >= t)) break;
                if (++guard >= SPIN_GUARD) break;     // converts stall into visible failure
                __builtin_amdgcn_s_sleep(1);
            }
        }

        // ---- A-fragments direct global->reg (coherent) ----
        f32x4 af[13];
        const char* ab = (t & 1) ? arb1 : arb0;
        LDA(0, "0")   LDA(1, "64")  LDA(2, "128") LDA(3, "192")
        LDA(4, "256") LDA(5, "320") LDA(6, "384") LDA(7, "448")
        LDA(8, "512") LDA(9, "576") LDA(10, "640") LDA(11, "704") LDA(12, "768")
        asm volatile("s_waitcnt vmcnt(0)" ::: "memory");
        __builtin_amdgcn_sched_barrier(0);

        // ---- z = h @ U_slice (two accumulator chains) ----
        f32x4 a0 = {0.f, 0.f, 0.f, 0.f}, a1 = {0.f, 0.f, 0.f, 0.f};
        #pragma unroll
        for (int kt = 0; kt < 13; kt += 2)
            a0 = __builtin_amdgcn_mfma_f32_16x16x32_bf16(
                     __builtin_bit_cast(bf16x8, af[kt]), barr[kt], a0, 0, 0, 0);
        #pragma unroll
        for (int kt = 1; kt < 13; kt += 2)
            a1 = __builtin_amdgcn_mfma_f32_16x16x32_bf16(
                     __builtin_bit_cast(bf16x8, af[kt]), barr[kt], a1, 0, 0, 0);
        f32x4 acc = a0 + a1;

        // ---- in-wave z exchange: (row,kg) thread gathers its 4 gate values ----
        // C layout: lane lm holds C[(lm>>4)*4+j][lm&15]; (row,cc) lives in
        // lane (row>>2)*16 + cc, reg j=row&3. This thread wants cc = kg*4+G.
        float zz[4];
        {
            float q0[4], q1[4], q2[4], q3[4];
            #pragma unroll
            for (int G = 0; G < 4; ++G) {
                q0[G] = __shfl(acc[0], S + G);
                q1[G] = __shfl(acc[1], S + G);
                q2[G] = __shfl(acc[2], S + G);
                q3[G] = __shfl(acc[3], S + G);
            }
            #pragma unroll
            for (int G = 0; G < 4; ++G) {
                float r = q0[G];
                r = (jj == 1) ? q1[G] : r;
                r = (jj == 2) ? q2[G] : r;
                r = (jj == 3) ? q3[G] : r;
                zz[G] = r + bz[G] + x0 * w0[G] + x1 * w1[G] + x2 * w2[G];
            }
        }

        // ---- pointwise peephole LSTM cell ----
        float iv = sigm(zz[0] + pi * cst);
        float fv = sigm(zz[1] + pf * cst);
        float cn = fv * cst + iv * tanhfast(zz[2]);
        float ov = sigm(zz[3] + po * cn);
        float h  = ov * tanhfast(cn);
        cst = cn;

        // ---- h broadcast: pack this wave's 4 units per row into one 8B store ----
        int hb = (int)f2bf(h);
        int h1 = __shfl_down(hb, 16);
        int h2 = __shfl_down(hb, 32);
        int h3 = __shfl_down(hb, 48);
        if (lane < 16) {
            unsigned int lo = (unsigned int)(hb & 0xffff) | ((unsigned int)(h1 & 0xffff) << 16);
            unsigned int hi = (unsigned int)(h2 & 0xffff) | ((unsigned int)(h3 & 0xffff) << 16);
            ull pk = (ull)lo | ((ull)hi << 32);
            ull* dst = (ull*)((t & 1) ? awb0 : awb1);   // write buf[(t+1)&1]
            __hip_atomic_store(dst, pk, __ATOMIC_RELAXED, __HIP_MEMORY_SCOPE_AGENT);
        }

        // ---- projection partials to LDS (parallel with store drain) ----
        float s0 = h * wd0, s1 = h * wd1, s2 = h * wd2;
        s0 += __shfl_xor(s0, 16); s0 += __shfl_xor(s0, 32);
        s1 += __shfl_xor(s1, 16); s1 += __shfl_xor(s1, 32);
        s2 += __shfl_xor(s2, 16); s2 += __shfl_xor(s2, 32);
        if (lane < 16) {
            redw[wid * (ROWS * 3) + lane * 3 + 0] = s0;
            redw[wid * (ROWS * 3) + lane * 3 + 1] = s1;
            redw[wid * (ROWS * 3) + lane * 3 + 2] = s2;
        }

        asm volatile("s_waitcnt vmcnt(0)" ::: "memory");   // h at LLC before barrier
        __syncthreads();                                   // all 5 waves' h drained + redw visible

        // ---- WG slot store (single plain store, no RMW chain) ----
        if (tid == 0)
            __hip_atomic_store(slotp, t + 1, __ATOMIC_RELAXED, __HIP_MEMORY_SCOPE_AGENT);

        // ---- WG-level output partial: 48 atomicAdds (off critical path) ----
        if (tid < 48) {
            int r = tid & 15, f = tid >> 4;
            float s = 0.f;
            #pragma unroll
            for (int w2 = 0; w2 < NW; ++w2) s += redw[w2 * (ROWS * 3) + r * 3 + f];
            atomicAdd(opp + (size_t)r * (TSTEPS * 3) + t * 3 + f, s);
        }
    }
}

// ---------------- merge: out = bd + sum of 5 slices ----------------
__global__ void merge_kernel(const float* __restrict__ outP, const float* __restrict__ bd,
                             float* __restrict__ out)
{
    int i = blockIdx.x * 256 + threadIdx.x;
    if (i >= OUTSZ) return;
    float s = bd[i % 3];
    #pragma unroll
    for (int k = 0; k < NSLICE; ++k) s += outP[(size_t)k * OUTSZ + i];
    out[i] = s;
}

// ---------------- launch ----------------
extern "C" void kernel_launch(void* const* d_in, const int* in_sizes, int n_in,
                              void* d_out, int out_size, void* d_ws, size_t ws_size,
                              hipStream_t stream)
{
    const float* x   = (const float*)d_in[0];
    const float* W   = (const float*)d_in[1];
    const float* U   = (const float*)d_in[2];
    const float* b   = (const float*)d_in[3];
    const float* p_i = (const float*)d_in[4];
    const float* p_f = (const float*)d_in[5];
    const float* p_o = (const float*)d_in[6];
    const float* Wd  = (const float*)d_in[7];
    const float* bd  = (const float*)d_in[8];
    float* out = (float*)d_out;

    char* p = (char*)d_ws;
    unsigned short* Urep = (unsigned short*)p;  p += (size_t)GATES * KCAP * 2;      // 1,433,600
    float* Wrep = (float*)p;                    p += (size_t)3 * GATES * 4;         // 19,200
    float* brep = (float*)p;                    p += (size_t)GATES * 4;             // 6,400
    unsigned short* Hbuf = (unsigned short*)p;  p += (size_t)2 * BATCH * KCAP * 2;  // 229,376
    int* flags = (int*)p;                       p += (size_t)NGROUP * 128 * 4;      // 4,096
    float* outP = (float*)p;                    p += (size_t)NSLICE * OUTSZ * 4;    // 7,680,000

    const int total = GATES * KCAP + 3 * GATES + GATES + 2 * BATCH * KCAP
                    + NGROUP * 128 + NSLICE * OUTSZ;
    const int iblocks = (total + 255) / 256;
    hipLaunchKernelGGL(hw_init_kernel, dim3(iblocks), dim3(256), 0, stream,
                       U, W, b, Urep, Wrep, brep, Hbuf, flags, outP);

    hipLaunchKernelGGL(lstm_kernel, dim3(NGROUP * CWG), dim3(NTHR), 0, stream,
                       x, p_i, p_f, p_o, Wd, Urep, Wrep, brep, Hbuf, flags, outP);

    hipLaunchKernelGGL(merge_kernel, dim3((OUTSZ + 255) / 256), dim3(256), 0, stream,
                       outP, bd, out);
}

// Round 6
// 3667.530 us; speedup vs baseline: 2.6053x; 1.0139x over previous
//
#include <hip/hip_runtime.h>
#include <hip/hip_bf16.h>

// ---------------- problem constants ----------------
#define UNITS   400
#define BATCH   128
#define TSTEPS  1000
#define GATES   1600            // 4*UNITS
#define KCAP2   480             // padded K: 15 MFMA k-tiles of 32 (>=400 zero in Urep)
#define NKT     15
#define NGROUP  8               // batch groups (128/16)
#define CWG     20              // WGs per group (each owns 20 units = 80 cols = 5 N-tiles)
#define SU      20
#define NW      5               // waves per WG (K-split: 3 k-tiles each)
#define NTHR    320
#define ROWS    16
#define SLOTS   120             // 16B slots per row (100 real + 20 pad)
#define RSLOTS  100
#define ROWB    (SLOTS*16)      // 1920 B per row
#define GRPB    (ROWS*ROWB)     // 30720 B per group
#define PARB    (NGROUP*GRPB)   // 245760 B per parity buffer
#define OUTSZ   (BATCH*TSTEPS*3)
#define NSLICE  5
#define SPIN_GUARD 16384

typedef __bf16 bf16x8 __attribute__((ext_vector_type(8)));
typedef float  f32x4  __attribute__((ext_vector_type(4)));
typedef unsigned int u32x4 __attribute__((ext_vector_type(4)));

__device__ __forceinline__ float sigm(float v)     { return 1.f / (1.f + __expf(-v)); }
__device__ __forceinline__ float tanhfast(float v) { return 1.f - 2.f / (1.f + __expf(2.f * v)); }

__device__ __forceinline__ unsigned int f2bf(float v) {
    __hip_bfloat16 h = __float2bfloat16(v);
    return (unsigned int)*reinterpret_cast<unsigned short*>(&h);
}

// ---------------- init / repack kernel ----------------
// Urep: [1600][480] bf16 k-major (col = unit*4 + gate), zero for k>=400
// Hep: 2 parity buffers of [8][16][120] 16B slots {h01, ep, h23, ep}; zeroed (ep=0 == step0)
__global__ void hw_init_kernel(const float* __restrict__ U, const float* __restrict__ W,
                               const float* __restrict__ b,
                               unsigned short* __restrict__ Urep, float* __restrict__ Wrep,
                               float* __restrict__ brep, int* __restrict__ Hep,
                               float* __restrict__ outP)
{
    int idx = blockIdx.x * 256 + threadIdx.x;
    if (idx < GATES * KCAP2) {
        int col = idx / KCAP2, k = idx - col * KCAP2;
        int u = col >> 2, G = col & 3;
        float v = (k < UNITS) ? U[k * GATES + G * UNITS + u] : 0.f;
        __hip_bfloat16 h = __float2bfloat16(v);
        Urep[idx] = *reinterpret_cast<unsigned short*>(&h);
        return;
    }
    idx -= GATES * KCAP2;
    if (idx < 3 * GATES) {
        int f = idx / GATES, col = idx - f * GATES;
        int u = col >> 2, G = col & 3;
        Wrep[idx] = W[f * GATES + G * UNITS + u];
        return;
    }
    idx -= 3 * GATES;
    if (idx < GATES) {
        int u = idx >> 2, G = idx & 3;
        brep[idx] = b[G * UNITS + u];
        return;
    }
    idx -= GATES;
    if (idx < 2 * PARB / 4) { Hep[idx] = 0; return; }
    idx -= 2 * PARB / 4;
    if (idx < NSLICE * OUTSZ) { outP[idx] = 0.f; return; }
}

// ---------------- persistent LSTM kernel ----------------
// 160 WGs x 320 threads. bid&7 = group (16 rows), bid>>3 = c (20 units = 5 slots).
// Waves K-split (3 k-tiles each); pointwise thread = (row=tid&15, u=tid>>4).
__global__ __launch_bounds__(NTHR, 1) void lstm_kernel(
    const float* __restrict__ x,                    // [128][1000][3]
    const float* __restrict__ p_i, const float* __restrict__ p_f, const float* __restrict__ p_o,
    const float* __restrict__ Wd,                   // [400][3]
    const unsigned short* __restrict__ Urep,        // [1600][480] bf16
    const float* __restrict__ Wrep, const float* __restrict__ brep,
    char* __restrict__ Hep,                         // 2 x PARB bytes
    float* __restrict__ outP)                       // [5][128][1000][3]
{
    __shared__ float zpart[NW * 5 * 64 * 4];        // 25.6 KB: [w][n][lane][j]
    __shared__ float redw[NW * ROWS * 3];           // 960 B

    const int tid  = threadIdx.x;
    const int lane = tid & 63, wid = tid >> 6;
    const int bid  = blockIdx.x;
    const int grp  = bid & 7;
    const int c    = bid >> 3;          // 0..19
    const int b0   = grp * ROWS;
    const int col0 = c * SU * 4;        // WG's repacked col base (80 cols)
    const int row  = lane & 15;         // MFMA A row role
    const int kg   = lane >> 4;         // 0..3 k-subgroup

    // ---- resident U B-fragments: 5 N-tiles x 3 k-tiles (this wave's K-slice) ----
    bf16x8 barr[5][3];
    #pragma unroll
    for (int n = 0; n < 5; ++n) {
        const unsigned short* up =
            Urep + (size_t)(col0 + n * 16 + row) * KCAP2 + (wid * 3) * 32 + kg * 8;
        #pragma unroll
        for (int kk = 0; kk < 3; ++kk)
            barr[n][kk] = *(const bf16x8*)(up + kk * 32);
    }

    // ---- slot-validity masks (pad slots never validated) ----
    bool rv[3][2];
    #pragma unroll
    for (int kk = 0; kk < 3; ++kk) {
        int s = 8 * (wid * 3 + kk) + 2 * kg;
        rv[kk][0] = (s     < RSLOTS);
        rv[kk][1] = (s + 1 < RSLOTS);
    }

    // ---- pointwise role constants (thread = (pr, pu)) ----
    const int pr = tid & 15;
    const int pu = tid >> 4;            // 0..19
    const int gu = c * SU + pu;
    float w0[4], w1[4], w2[4], bz[4];
    #pragma unroll
    for (int G = 0; G < 4; ++G) {
        w0[G] = Wrep[0 * GATES + gu * 4 + G];
        w1[G] = Wrep[1 * GATES + gu * 4 + G];
        w2[G] = Wrep[2 * GATES + gu * 4 + G];
        bz[G] = brep[gu * 4 + G];
    }
    const float pi = p_i[gu], pf = p_f[gu], po = p_o[gu];
    const float wd0 = Wd[gu * 3 + 0], wd1 = Wd[gu * 3 + 1], wd2 = Wd[gu * 3 + 2];

    // ---- addresses ----
    // load base: row (lane&15), this wave's k-slice, kg offset
    const char* ldb0 = Hep + grp * GRPB + (size_t)row * ROWB + wid * 384 + kg * 32;
    const char* ldb1 = ldb0 + PARB;
    // store base: lane<16 stores row=lane, slot c*5+wid
    char* stb0 = Hep + grp * GRPB + (size_t)lane * ROWB + (c * 5 + wid) * 16;
    char* stb1 = stb0 + PARB;

    const float* xp = x + (size_t)(b0 + pr) * (TSTEPS * 3);
    float* opp = outP + (size_t)(c % NSLICE) * OUTSZ + (size_t)b0 * (TSTEPS * 3);

    float cst = 0.f;

    #pragma unroll 1
    for (int t = 0; t < TSTEPS; ++t) {
        // x for this step (issues early, off critical path)
        float x0 = xp[t * 3 + 0], x1 = xp[t * 3 + 1], x2 = xp[t * 3 + 2];

        // ---- speculative validated loads: slots carry their own epoch ----
        u32x4 sa0, sb0, sa1, sb1, sa2, sb2;
        {
            const char* ab = (t & 1) ? ldb1 : ldb0;
            const unsigned int te = (unsigned int)t;
            int guard = 0;
            for (;;) {
                asm volatile("global_load_dwordx4 %0, %1, off sc0 sc1"
                             : "=v"(sa0) : "v"(ab) : "memory");
                asm volatile("global_load_dwordx4 %0, %1, off offset:16 sc0 sc1"
                             : "=v"(sb0) : "v"(ab) : "memory");
                asm volatile("global_load_dwordx4 %0, %1, off offset:128 sc0 sc1"
                             : "=v"(sa1) : "v"(ab) : "memory");
                asm volatile("global_load_dwordx4 %0, %1, off offset:144 sc0 sc1"
                             : "=v"(sb1) : "v"(ab) : "memory");
                asm volatile("global_load_dwordx4 %0, %1, off offset:256 sc0 sc1"
                             : "=v"(sa2) : "v"(ab) : "memory");
                asm volatile("global_load_dwordx4 %0, %1, off offset:272 sc0 sc1"
                             : "=v"(sb2) : "v"(ab) : "memory");
                asm volatile("s_waitcnt vmcnt(0)" ::: "memory");
                bool ok = (!rv[0][0] || (sa0[1] == te && sa0[3] == te))
                       && (!rv[0][1] || (sb0[1] == te && sb0[3] == te))
                       && (!rv[1][0] || (sa1[1] == te && sa1[3] == te))
                       && (!rv[1][1] || (sb1[1] == te && sb1[3] == te))
                       && (!rv[2][0] || (sa2[1] == te && sa2[3] == te))
                       && (!rv[2][1] || (sb2[1] == te && sb2[3] == te));
                if (__all((int)ok)) break;
                if (++guard >= SPIN_GUARD) break;   // stall -> visible failure, not hang
                __builtin_amdgcn_s_sleep(1);
            }
        }

        // ---- partial z over this wave's 3 k-tiles, 5 N-tiles ----
        f32x4 acc[5] = {};
        {
            u32x4 f0 = {sa0[0], sa0[2], sb0[0], sb0[2]};
            u32x4 f1 = {sa1[0], sa1[2], sb1[0], sb1[2]};
            u32x4 f2 = {sa2[0], sa2[2], sb2[0], sb2[2]};
            bf16x8 a0 = __builtin_bit_cast(bf16x8, f0);
            bf16x8 a1 = __builtin_bit_cast(bf16x8, f1);
            bf16x8 a2 = __builtin_bit_cast(bf16x8, f2);
            #pragma unroll
            for (int n = 0; n < 5; ++n) {
                acc[n] = __builtin_amdgcn_mfma_f32_16x16x32_bf16(a0, barr[n][0], acc[n], 0, 0, 0);
                acc[n] = __builtin_amdgcn_mfma_f32_16x16x32_bf16(a1, barr[n][1], acc[n], 0, 0, 0);
                acc[n] = __builtin_amdgcn_mfma_f32_16x16x32_bf16(a2, barr[n][2], acc[n], 0, 0, 0);
            }
        }
        #pragma unroll
        for (int n = 0; n < 5; ++n)
            *(f32x4*)&zpart[(((wid * 5) + n) * 64 + lane) * 4] = acc[n];
        __syncthreads();

        // ---- pointwise: gather z (sum 5 wave-partials from LDS), cell update ----
        float zz[4];
        #pragma unroll
        for (int G = 0; G < 4; ++G) {
            int cc = pu * 4 + G;
            int n  = cc >> 4;
            int ls = ((pr >> 2) << 4) + (cc & 15);
            int j  = pr & 3;
            float s = 0.f;
            #pragma unroll
            for (int w = 0; w < NW; ++w)
                s += zpart[(((w * 5) + n) * 64 + ls) * 4 + j];
            zz[G] = s + bz[G] + x0 * w0[G] + x1 * w1[G] + x2 * w2[G];
        }
        float iv = sigm(zz[0] + pi * cst);
        float fv = sigm(zz[1] + pf * cst);
        float cn = fv * cst + iv * tanhfast(zz[2]);
        float ov = sigm(zz[3] + po * cn);
        float h  = ov * tanhfast(cn);
        cst = cn;

        // ---- h slot store: {h01, ep, h23, ep} per (row, 4 units) — self-validating ----
        unsigned int hb = f2bf(h);
        unsigned int h1 = __shfl_down((int)hb, 16);
        unsigned int h2 = __shfl_down((int)hb, 32);
        unsigned int h3 = __shfl_down((int)hb, 48);
        if (lane < 16) {
            unsigned int lo = (hb & 0xffffu) | (h1 << 16);
            unsigned int hi = (h2 & 0xffffu) | (h3 << 16);
            u32x4 sv = {lo, (unsigned int)(t + 1), hi, (unsigned int)(t + 1)};
            char* dst = (t & 1) ? stb0 : stb1;      // write buf[(t+1)&1]
            asm volatile("global_store_dwordx4 %0, %1, off sc0 sc1"
                         :: "v"(dst), "v"(sv) : "memory");
        }

        // ---- fused projection partials ----
        float s0 = h * wd0, s1 = h * wd1, s2 = h * wd2;
        s0 += __shfl_xor(s0, 16); s0 += __shfl_xor(s0, 32);
        s1 += __shfl_xor(s1, 16); s1 += __shfl_xor(s1, 32);
        s2 += __shfl_xor(s2, 16); s2 += __shfl_xor(s2, 32);
        if (lane < 16) {
            redw[wid * (ROWS * 3) + lane * 3 + 0] = s0;
            redw[wid * (ROWS * 3) + lane * 3 + 1] = s1;
            redw[wid * (ROWS * 3) + lane * 3 + 2] = s2;
        }
        __syncthreads();    // redw visible; also fences zpart reuse next step
        if (tid < 48) {
            int r = tid & 15, f = tid >> 4;
            float s = 0.f;
            #pragma unroll
            for (int w2 = 0; w2 < NW; ++w2) s += redw[w2 * (ROWS * 3) + r * 3 + f];
            atomicAdd(opp + (size_t)r * (TSTEPS * 3) + t * 3 + f, s);
        }
    }
}

// ---------------- merge: out = bd + sum of 5 slices ----------------
__global__ void merge_kernel(const float* __restrict__ outP, const float* __restrict__ bd,
                             float* __restrict__ out)
{
    int i = blockIdx.x * 256 + threadIdx.x;
    if (i >= OUTSZ) return;
    float s = bd[i % 3];
    #pragma unroll
    for (int k = 0; k < NSLICE; ++k) s += outP[(size_t)k * OUTSZ + i];
    out[i] = s;
}

// ---------------- launch ----------------
extern "C" void kernel_launch(void* const* d_in, const int* in_sizes, int n_in,
                              void* d_out, int out_size, void* d_ws, size_t ws_size,
                              hipStream_t stream)
{
    const float* x   = (const float*)d_in[0];
    const float* W   = (const float*)d_in[1];
    const float* U   = (const float*)d_in[2];
    const float* b   = (const float*)d_in[3];
    const float* p_i = (const float*)d_in[4];
    const float* p_f = (const float*)d_in[5];
    const float* p_o = (const float*)d_in[6];
    const float* Wd  = (const float*)d_in[7];
    const float* bd  = (const float*)d_in[8];
    float* out = (float*)d_out;

    char* p = (char*)d_ws;
    unsigned short* Urep = (unsigned short*)p;  p += (size_t)GATES * KCAP2 * 2;     // 1,536,000
    float* Wrep = (float*)p;                    p += (size_t)3 * GATES * 4;         // 19,200
    float* brep = (float*)p;                    p += (size_t)GATES * 4;             // 6,400
    char* Hep = p;                              p += (size_t)2 * PARB;              // 491,520
    float* outP = (float*)p;                    p += (size_t)NSLICE * OUTSZ * 4;    // 7,680,000

    const int total = GATES * KCAP2 + 3 * GATES + GATES + 2 * PARB / 4 + NSLICE * OUTSZ;
    const int iblocks = (total + 255) / 256;
    hipLaunchKernelGGL(hw_init_kernel, dim3(iblocks), dim3(256), 0, stream,
                       U, W, b, Urep, Wrep, brep, (int*)Hep, outP);

    hipLaunchKernelGGL(lstm_kernel, dim3(NGROUP * CWG), dim3(NTHR), 0, stream,
                       x, p_i, p_f, p_o, Wd, Urep, Wrep, brep, Hep, outP);

    hipLaunchKernelGGL(merge_kernel, dim3((OUTSZ + 255) / 256), dim3(256), 0, stream,
                       outP, bd, out);
}